// Round 3
// baseline (290.164 us; speedup 1.0000x reference)
//
#include <hip/hip_runtime.h>
#include <math.h>

// CovidModel: M[t][s] = sum_j A_full[J+t-1-j][s] * rho[s] * pi[j][s]
// Closed form kills the sequential scan:
//   A[d][s] = A0[s] * exp2(invT[s]*L[d] + (d+1)*log2(delta[s]))
//   L[d] = prefix sum of log2(r_t)  (sample-independent, in d_ws)
// R3: 2 samples/thread as float2 -> v_pk_fma_f32 (half the VALU issue),
// dwordx2 stores, and launch_bounds(256,3) (~170 VGPR cap) so the
// w[32]+ring[32] float2 arrays live in registers WITHOUT spilling
// (R2's (256,4)=128-reg cap is the suspected scratch-spill source).

#define T_DAYS 1024
#define J_WIN  32
#define DT     32    // days per block chunk == J_WIN (ring does one full turn)

typedef float v2f __attribute__((ext_vector_type(2)));

// Kernel 1: L[t] = inclusive prefix sum of log2(r_t[t]); one block.
__global__ void prefix_log_kernel(const float* __restrict__ r_t,
                                  float* __restrict__ L) {
    __shared__ float buf[T_DAYS];
    const int i = threadIdx.x;
    buf[i] = __log2f(r_t[i]);
    __syncthreads();
    for (int off = 1; off < T_DAYS; off <<= 1) {
        float add = (i >= off) ? buf[i - off] : 0.0f;
        __syncthreads();
        buf[i] += add;
        __syncthreads();
    }
    L[i] = buf[i];
}

// Kernel 2: main forecast. TWO samples per lane (float2), 32 days per block.
__global__ __launch_bounds__(256, 3)
void covid_kernel(const float* __restrict__ warmup_A,
                  const float* __restrict__ delta_p,
                  const float* __restrict__ T_serial,
                  const float* __restrict__ rho_p,
                  const float* __restrict__ pi_M,
                  const float* __restrict__ L,
                  float* __restrict__ out,
                  int S) {
    const int s  = (blockIdx.x * 256 + threadIdx.x) * 2;  // even; S=50000 even
    const int t0 = blockIdx.y * DT;                       // multiple of 32

    // L window this block needs: days [t0-32, t0+32)
    __shared__ float Lsh[2 * J_WIN];
    for (int k = threadIdx.x; k < 2 * J_WIN; k += 256) {
        int d = t0 - J_WIN + k;
        Lsh[k] = (d >= 0) ? L[d] : 0.0f;
    }
    __syncthreads();
    if (s >= S) return;

    // float2 loads of per-sample params (8B-aligned: rows even-length, s even)
    const v2f Ts   = *(const v2f*)&T_serial[s];
    const v2f dlt  = *(const v2f*)&delta_p[s];
    const v2f rhov = *(const v2f*)&rho_p[s];
    const v2f A0   = *(const v2f*)&warmup_A[(J_WIN - 1) * S + s];
    v2f invT; invT.x = 1.0f / Ts.x; invT.y = 1.0f / Ts.y;
    v2f ld;   ld.x = __log2f(dlt.x); ld.y = __log2f(dlt.y);
    const float t0f = (float)t0;

    // Folded weights w[j] = rho * pi[j][s..s+1] (registers)
    v2f w[J_WIN];
#pragma unroll
    for (int j = 0; j < J_WIN; ++j)
        w[j] = rhov * (*(const v2f*)&pi_M[j * S + s]);

    // Ring: A(day d) at ring[d mod 32] (warmup day d<0 at d+32).
    v2f ring[J_WIN];
    if (t0 == 0) {
#pragma unroll
        for (int k = 0; k < J_WIN; ++k)
            ring[k] = *(const v2f*)&warmup_A[k * S + s];
    } else {
#pragma unroll
        for (int k = 0; k < J_WIN; ++k) {
            const float df = t0f - (float)J_WIN + (float)(k + 1);
            v2f arg = __builtin_elementwise_fma(invT, (v2f)(Lsh[k]), df * ld);
            v2f e; e.x = __builtin_amdgcn_exp2f(arg.x);
                   e.y = __builtin_amdgcn_exp2f(arg.y);
            ring[k] = A0 * e;
        }
    }

    float* op = out + (size_t)t0 * S + s;
#pragma unroll
    for (int u = 0; u < DT; ++u) {
        // M[t0+u] = sum_j w[j] * A(t0+u-1-j); ring slot indices are
        // compile-time constants after unrolling -> pure v_pk_fma_f32.
        v2f m0 = (v2f)0.0f, m1 = (v2f)0.0f, m2 = (v2f)0.0f, m3 = (v2f)0.0f;
#pragma unroll
        for (int j = 0; j < J_WIN; j += 4) {
            m0 = __builtin_elementwise_fma(w[j + 0], ring[(u - 1 - j) & 31], m0);
            m1 = __builtin_elementwise_fma(w[j + 1], ring[(u - 2 - j) & 31], m1);
            m2 = __builtin_elementwise_fma(w[j + 2], ring[(u - 3 - j) & 31], m2);
            m3 = __builtin_elementwise_fma(w[j + 3], ring[(u - 4 - j) & 31], m3);
        }
        *(v2f*)&op[(size_t)u * S] = (m0 + m1) + (m2 + m3);
        // A(t0+u) closed form; overwrites oldest slot (day t0+u-32).
        v2f arg = __builtin_elementwise_fma(
            invT, (v2f)(Lsh[J_WIN + u]), (t0f + (float)(u + 1)) * ld);
        v2f e; e.x = __builtin_amdgcn_exp2f(arg.x);
               e.y = __builtin_amdgcn_exp2f(arg.y);
        ring[u] = A0 * e;
    }
}

extern "C" void kernel_launch(void* const* d_in, const int* in_sizes, int n_in,
                              void* d_out, int out_size, void* d_ws, size_t ws_size,
                              hipStream_t stream) {
    const float* r_t      = (const float*)d_in[0];
    const float* warmup_A = (const float*)d_in[1];
    const float* delta    = (const float*)d_in[2];
    const float* T_serial = (const float*)d_in[3];
    const float* rho_M    = (const float*)d_in[4];
    const float* pi_M     = (const float*)d_in[5];
    float* out = (float*)d_out;
    float* L   = (float*)d_ws;          // T_DAYS floats of scratch
    const int S = in_sizes[2];          // 50000 (even)

    prefix_log_kernel<<<1, T_DAYS, 0, stream>>>(r_t, L);

    const int pairs = S / 2;
    dim3 grid((pairs + 255) / 256, T_DAYS / DT);
    covid_kernel<<<grid, 256, 0, stream>>>(warmup_A, delta, T_serial, rho_M,
                                           pi_M, L, out, S);
}

// Round 4
// 272.940 us; speedup vs baseline: 1.0631x; 1.0631x over previous
//
#include <hip/hip_runtime.h>
#include <math.h>

// CovidModel: M[t][s] = sum_j A_full[J+t-1-j][s] * rho[s] * pi[j][s]
// Closed form kills the sequential scan:
//   A[d][s] = A0[s] * exp2(invT[s]*L[d] + (d+1)*log2(delta[s]))
//   L[d] = prefix sum of log2(r_t)  (block-uniform -> SGPRs, in d_ws)
// R4: scalar 1 sample/thread (R3's float2 blew the register file). Register
// discipline so w[32]+ring[32] (+~16 temps) fits the (256,4) 128-VGPR cap
// with no spills:
//   - L window read via uniform loads + readfirstlane -> SGPRs (the R2 LDS
//     version let the scheduler hoist 32 ds_reads into 32 VGPRs)
//   - incremental store pointer + incremental day-exponent (no 32 hoisted
//     64-bit address pairs / convert+mul per day)
//   - rho folded into A0 (one mul) instead of w[] (32 muls)

#define T_DAYS 1024
#define J_WIN  32
#define DT     32    // days per block; ring slot indices stay compile-time

__device__ __forceinline__ float uload(const float* p) {
    // Block-uniform load -> force into SGPR so it costs no VGPR when hoisted.
    return __int_as_float(__builtin_amdgcn_readfirstlane(__float_as_int(*p)));
}

// Kernel 1: Lbuf[32+t] = inclusive prefix sum of log2(r_t[t]); Lbuf[0..31]=0.
__global__ void prefix_log_kernel(const float* __restrict__ r_t,
                                  float* __restrict__ Lbuf) {
    __shared__ float buf[T_DAYS];
    const int i = threadIdx.x;
    buf[i] = __log2f(r_t[i]);
    __syncthreads();
    for (int off = 1; off < T_DAYS; off <<= 1) {
        float add = (i >= off) ? buf[i - off] : 0.0f;
        __syncthreads();
        buf[i] += add;
        __syncthreads();
    }
    Lbuf[J_WIN + i] = buf[i];
    if (i < J_WIN) Lbuf[i] = 0.0f;   // pad: L[d]=0 for d<0
}

// Kernel 2: main forecast. One sample per lane, 32 days per block.
__global__ __launch_bounds__(256, 4)
void covid_kernel(const float* __restrict__ warmup_A,
                  const float* __restrict__ delta_p,
                  const float* __restrict__ T_serial,
                  const float* __restrict__ rho_p,
                  const float* __restrict__ pi_M,
                  const float* __restrict__ Lbuf,
                  float* __restrict__ out,
                  int S) {
    const int s  = blockIdx.x * 256 + threadIdx.x;
    const int t0 = blockIdx.y * DT;          // multiple of 32, block-uniform
    if (s >= S) return;

    const float invT = 1.0f / T_serial[s];
    const float ld   = __log2f(delta_p[s]);
    // rho folded into the A-scale: ring holds rho*A; M = sum pi[j]*ring.
    const float A0   = rho_p[s] * warmup_A[(J_WIN - 1) * S + s];
    const float t0f  = (float)t0;

    // Weights: plain pi (rho already folded into A0). 32 VGPRs.
    float w[J_WIN];
#pragma unroll
    for (int j = 0; j < J_WIN; ++j) w[j] = pi_M[j * S + s];

    // Ring: (rho-scaled) A(day d) at slot d mod 32; warmup day d<0 at d+32.
    // Lbuf[32+d] = L[d]; init window days t0-32+k -> Lbuf[t0+k] (>=0, uniform).
    float ring[J_WIN];
    if (t0 == 0) {
        const float rho = rho_p[s];
#pragma unroll
        for (int k = 0; k < J_WIN; ++k) ring[k] = rho * warmup_A[k * S + s];
    } else {
#pragma unroll
        for (int k = 0; k < J_WIN; ++k) {
            float arg = fmaf(invT, uload(&Lbuf[t0 + k]),
                             (t0f - (float)J_WIN + (float)(k + 1)) * ld);
            ring[k] = A0 * __builtin_amdgcn_exp2f(arg);
        }
    }

    const float* Ld = Lbuf + J_WIN + t0;     // Ld[u] = L[t0+u], uniform
    float* op   = out + (size_t)t0 * S + s;  // incremental store pointer
    float cday  = (t0f + 1.0f) * ld;         // (t+1)*ld for u=0
#pragma unroll
    for (int u = 0; u < DT; ++u) {
        // M[t0+u] = sum_j w[j] * ring[(u-1-j)&31]; indices compile-time.
        float m0 = 0.0f, m1 = 0.0f, m2 = 0.0f, m3 = 0.0f;
#pragma unroll
        for (int j = 0; j < J_WIN; j += 4) {
            m0 = fmaf(w[j + 0], ring[(u - 1 - j) & 31], m0);
            m1 = fmaf(w[j + 1], ring[(u - 2 - j) & 31], m1);
            m2 = fmaf(w[j + 2], ring[(u - 3 - j) & 31], m2);
            m3 = fmaf(w[j + 3], ring[(u - 4 - j) & 31], m3);
        }
        *op = (m0 + m1) + (m2 + m3);
        op += S;
        // A(t0+u) closed form; overwrites oldest slot (day t0+u-32).
        ring[u] = A0 * __builtin_amdgcn_exp2f(fmaf(invT, uload(&Ld[u]), cday));
        cday += ld;
    }
}

extern "C" void kernel_launch(void* const* d_in, const int* in_sizes, int n_in,
                              void* d_out, int out_size, void* d_ws, size_t ws_size,
                              hipStream_t stream) {
    const float* r_t      = (const float*)d_in[0];
    const float* warmup_A = (const float*)d_in[1];
    const float* delta    = (const float*)d_in[2];
    const float* T_serial = (const float*)d_in[3];
    const float* rho_M    = (const float*)d_in[4];
    const float* pi_M     = (const float*)d_in[5];
    float* out  = (float*)d_out;
    float* Lbuf = (float*)d_ws;         // (32 pad + 1024) floats of scratch
    const int S = in_sizes[2];          // 50000

    prefix_log_kernel<<<1, T_DAYS, 0, stream>>>(r_t, Lbuf);

    dim3 grid((S + 255) / 256, T_DAYS / DT);
    covid_kernel<<<grid, 256, 0, stream>>>(warmup_A, delta, T_serial, rho_M,
                                           pi_M, Lbuf, out, S);
}